// Round 8
// baseline (427.830 us; speedup 1.0000x reference)
//
#include <hip/hip_runtime.h>
#include <hip/hip_bf16.h>

#define NN 100000
#define NE 1600000
#define NB 391      // buckets of 256 nodes: (100000 + 255) >> 8
#define CHUNK 4096  // edges per partition block

typedef short bf8v __attribute__((ext_vector_type(8)));   // 8 bf16 (4 VGPRs)
typedef float f32x4 __attribute__((ext_vector_type(4)));  // MFMA acc

static __device__ __forceinline__ float lrelu(float x, float s) {
    return x > 0.f ? x : s * x;
}

static __device__ __forceinline__ unsigned short f2b(float f) {
    __hip_bfloat16 b = __float2bfloat16(f);
    return *reinterpret_cast<unsigned short*>(&b);
}

static __device__ __forceinline__ float blo(unsigned u) {
    return __uint_as_float(u << 16);
}
static __device__ __forceinline__ float bhi(unsigned u) {
    return __uint_as_float(u & 0xFFFF0000u);
}

// ---------------- CSR build: two-level counting sort ----------------

__global__ __launch_bounds__(256) void bucket_hist(const int* __restrict__ dsts,
                                                   int* __restrict__ bcnt) {
    __shared__ int hist[NB];
    for (int t = threadIdx.x; t < NB; t += 256) hist[t] = 0;
    __syncthreads();
    int stride = gridDim.x * 256;
    for (int e = blockIdx.x * 256 + threadIdx.x; e < NE; e += stride)
        atomicAdd(&hist[dsts[e] >> 8], 1);
    __syncthreads();
    for (int t = threadIdx.x; t < NB; t += 256) {
        int c = hist[t];
        if (c) atomicAdd(&bcnt[t], c);
    }
}

__global__ __launch_bounds__(512) void bucket_scan(const int* __restrict__ bcnt,
                                                   int* __restrict__ bbase,
                                                   int* __restrict__ bcursor) {
    __shared__ int sd[512];
    int t = threadIdx.x;
    int v = (t < NB) ? bcnt[t] : 0;
    sd[t] = v;
    __syncthreads();
    for (int off = 1; off < 512; off <<= 1) {
        int x = (t >= off) ? sd[t - off] : 0;
        __syncthreads();
        sd[t] += x;
        __syncthreads();
    }
    int excl = sd[t] - v;
    if (t < NB) {
        bbase[t] = excl;
        bcursor[t] = excl;
    }
    if (t == NB - 1) bbase[NB] = excl + v;
}

__global__ __launch_bounds__(256) void partition_kernel(const int* __restrict__ srcs,
                                                        const int* __restrict__ dsts,
                                                        int* bcursor,
                                                        int2* __restrict__ part) {
    __shared__ int hist[NB];
    __shared__ int lbase[NB];
    for (int t = threadIdx.x; t < NB; t += 256) hist[t] = 0;
    __syncthreads();
    int e0 = blockIdx.x * CHUNK;
#pragma unroll
    for (int k = 0; k < CHUNK / 256; k++) {
        int e = e0 + k * 256 + threadIdx.x;
        if (e < NE) atomicAdd(&hist[dsts[e] >> 8], 1);
    }
    __syncthreads();
    for (int t = threadIdx.x; t < NB; t += 256) {
        int c = hist[t];
        if (c) lbase[t] = atomicAdd(&bcursor[t], c);
        hist[t] = 0;  // reuse as local cursor
    }
    __syncthreads();
#pragma unroll
    for (int k = 0; k < CHUNK / 256; k++) {
        int e = e0 + k * 256 + threadIdx.x;
        if (e < NE) {
            int s = srcs[e], d = dsts[e];
            int b = d >> 8;
            int r = atomicAdd(&hist[b], 1);
            part[lbase[b] + r] = make_int2(s, d);
        }
    }
}

__global__ __launch_bounds__(256) void bucket_fill(const int2* __restrict__ part,
                                                   const int* __restrict__ bbase,
                                                   int* __restrict__ offs,
                                                   int* __restrict__ csr) {
    __shared__ int lcur[256];
    __shared__ int sd[256];
    int b = blockIdx.x;
    int t = threadIdx.x;
    int ebeg = bbase[b], eend = bbase[b + 1];
    int node0 = b << 8;
    int nNodes = min(256, NN - node0);
    lcur[t] = 0;
    __syncthreads();
    for (int e = ebeg + t; e < eend; e += 256) {
        int2 p = part[e];
        atomicAdd(&lcur[p.y - node0], 1);
    }
    __syncthreads();
    int cnt = lcur[t];
    sd[t] = cnt;
    __syncthreads();
    for (int off = 1; off < 256; off <<= 1) {
        int x = (t >= off) ? sd[t - off] : 0;
        __syncthreads();
        sd[t] += x;
        __syncthreads();
    }
    int start = ebeg + sd[t] - cnt;
    if (t < nNodes) offs[node0 + t] = start;
    if (b == NB - 1 && t == 0) offs[NN] = NE;
    lcur[t] = start;
    __syncthreads();
    for (int e = ebeg + t; e < eend; e += 256) {
        int2 p = part[e];
        int pos = atomicAdd(&lcur[p.y - node0], 1);
        csr[pos] = p.x;
    }
}

// ---------------- fused MFMA GEMM + attention coefficients ----------------

template <int NOUT, int HEADS, bool AF32>
__global__ __launch_bounds__(256) void gemm_fused(
    const float* __restrict__ A32, const unsigned short* __restrict__ A16,
    const float* __restrict__ W, const float* __restrict__ asrc,
    const float* __restrict__ adst, unsigned short* __restrict__ h16out,
    float* __restrict__ als, float* __restrict__ ald, int n) {
    constexpr int NF = NOUT / 16;
    constexpr int PITCH = 136;
    __shared__ unsigned short Wl[NOUT * PITCH];

    const int tid = threadIdx.x;
    for (int i = tid; i < (128 * NOUT) / 4; i += 256) {
        int idx = i * 4;
        int k = idx / NOUT;
        int c = idx - k * NOUT;
        float4 wv = *(const float4*)&W[idx];
        Wl[(c + 0) * PITCH + k] = f2b(wv.x);
        Wl[(c + 1) * PITCH + k] = f2b(wv.y);
        Wl[(c + 2) * PITCH + k] = f2b(wv.z);
        Wl[(c + 3) * PITCH + k] = f2b(wv.w);
    }
    __syncthreads();

    const int lane = tid & 63, wave = tid >> 6;
    const int c = lane & 15, hi = lane >> 4;
    const int r0 = blockIdx.x * 64;
    const int arow = min(r0 + wave * 16 + c, n - 1);
    const int kb = hi * 8;

    f32x4 acc[NF];
#pragma unroll
    for (int nf = 0; nf < NF; ++nf) acc[nf] = 0;

#pragma unroll
    for (int kc = 0; kc < 4; ++kc) {
        bf8v a;
        if constexpr (AF32) {
            const float* ap = A32 + (size_t)arow * 128 + kc * 32 + kb;
            float4 f0 = *(const float4*)ap;
            float4 f1 = *(const float4*)(ap + 4);
            union {
                bf8v v;
                unsigned short u[8];
            } ua;
            ua.u[0] = f2b(f0.x);
            ua.u[1] = f2b(f0.y);
            ua.u[2] = f2b(f0.z);
            ua.u[3] = f2b(f0.w);
            ua.u[4] = f2b(f1.x);
            ua.u[5] = f2b(f1.y);
            ua.u[6] = f2b(f1.z);
            ua.u[7] = f2b(f1.w);
            a = ua.v;
        } else {
            a = *(const bf8v*)(A16 + (size_t)arow * 128 + kc * 32 + kb);
        }
#pragma unroll
        for (int nf = 0; nf < NF; ++nf) {
            bf8v b = *(const bf8v*)&Wl[(nf * 16 + c) * PITCH + kc * 32 + kb];
            acc[nf] = __builtin_amdgcn_mfma_f32_16x16x32_bf16(a, b, acc[nf], 0, 0, 0);
        }
    }

    // epilogue 1: als/ald from accumulators
    float aS[NF], aD[NF];
#pragma unroll
    for (int nf = 0; nf < NF; ++nf) {
        aS[nf] = asrc[nf * 16 + c];
        aD[nf] = adst[nf * 16 + c];
    }
    float sRes[HEADS][4], dRes[HEADS][4];
#pragma unroll
    for (int hh = 0; hh < HEADS; ++hh) {
#pragma unroll
        for (int reg = 0; reg < 4; ++reg) {
            float s = 0.f, d = 0.f;
#pragma unroll
            for (int nf = hh * (NF / HEADS); nf < (hh + 1) * (NF / HEADS); ++nf) {
                s += acc[nf][reg] * aS[nf];
                d += acc[nf][reg] * aD[nf];
            }
#pragma unroll
            for (int o = 1; o < 16; o <<= 1) {
                s += __shfl_xor(s, o);
                d += __shfl_xor(d, o);
            }
            sRes[hh][reg] = s;
            dRes[hh][reg] = d;
        }
    }
    if (c == 0) {
#pragma unroll
        for (int reg = 0; reg < 4; ++reg) {
            int ro = r0 + wave * 16 + hi * 4 + reg;
            if (ro < n) {
                if constexpr (HEADS == 4) {
                    *(float4*)&als[ro * 4] =
                        make_float4(sRes[0][reg], sRes[1][reg], sRes[2][reg], sRes[3][reg]);
                    *(float4*)&ald[ro * 4] =
                        make_float4(dRes[0][reg], dRes[1][reg], dRes[2][reg], dRes[3][reg]);
                } else {
                    als[ro] = sRes[0][reg];
                    ald[ro] = dRes[0][reg];
                }
            }
        }
    }

    // epilogue 2: h -> bf16 via LDS transpose, coalesced store
    __syncthreads();
#pragma unroll
    for (int nf = 0; nf < NF; ++nf) {
#pragma unroll
        for (int reg = 0; reg < 4; ++reg) {
            int rl = wave * 16 + hi * 4 + reg;
            Wl[rl * PITCH + nf * 16 + c] = f2b(acc[nf][reg]);
        }
    }
    __syncthreads();
    constexpr int SEGS = NOUT / 8;
    for (int i = tid; i < 64 * SEGS; i += 256) {
        int rl = i / SEGS, sg = i - rl * SEGS;
        int ro = r0 + rl;
        if (ro < n)
            *(uint4*)&h16out[(size_t)ro * NOUT + sg * 8] =
                *(const uint4*)&Wl[rl * PITCH + sg * 8];
    }
}

// ---------------- GAT aggregation, 4 heads (F=128), wave per dst node -------------
// Half-wave (32 lanes) per edge, dwordx2 gather (4 feats/lane), 8 pairs (16 edges)
// unrolled per iteration -> 8 gather chains in flight per lane.
// Self-loop seeded in half 0 ONLY (halves summed at the end).

__global__ __launch_bounds__(256) void agg4_kernel(
    const char* __restrict__ hb, const float* __restrict__ als, const float* __restrict__ ald,
    const int* __restrict__ offs, const int* __restrict__ cur, const int* __restrict__ csr,
    const float* __restrict__ bias, __hip_bfloat16* __restrict__ out, int n, int do_l1) {
    __shared__ int soff[4][64];
    __shared__ float sp[4][64][4];
    int w = threadIdx.x >> 6;
    int v = blockIdx.x * 4 + w;
    if (v >= n) return;
    int lane = threadIdx.x & 63;
    int half = lane >> 5;
    int sl = lane & 31;
    int hd = sl >> 3;
    int fb = sl << 3;  // byte offset of this lane's 4 features

    float4 av = *(const float4*)&ald[v * 4];
    float4 svv = *(const float4*)&als[v * 4];
    int begin = offs[v], end = cur[v];

    float ps0 = __expf(lrelu(svv.x + av.x, 0.2f));
    float ps1 = __expf(lrelu(svv.y + av.y, 0.2f));
    float ps2 = __expf(lrelu(svv.z + av.z, 0.2f));
    float ps3 = __expf(lrelu(svv.w + av.w, 0.2f));
    float psel = hd == 0 ? ps0 : hd == 1 ? ps1 : hd == 2 ? ps2 : ps3;
    float pseed = (half == 0) ? psel : 0.f;  // self-loop once across halves
    uint2 uv = *(const uint2*)(hb + (size_t)v * 256 + fb);
    float acc0 = pseed * blo(uv.x);
    float acc1 = pseed * bhi(uv.x);
    float acc2 = pseed * blo(uv.y);
    float acc3 = pseed * bhi(uv.y);
    float s0 = 0.f, s1 = 0.f, s2 = 0.f, s3 = 0.f;

    for (int base = begin; base < end; base += 64) {
        int idx = base + lane;
        int cnt = min(64, end - base);
        if (idx < end) {
            int s = csr[idx];
            float4 q = *(const float4*)&als[s * 4];
            float p0 = __expf(lrelu(q.x + av.x, 0.2f));
            float p1 = __expf(lrelu(q.y + av.y, 0.2f));
            float p2 = __expf(lrelu(q.z + av.z, 0.2f));
            float p3 = __expf(lrelu(q.w + av.w, 0.2f));
            soff[w][lane] = s << 8;
            sp[w][lane][0] = p0;
            sp[w][lane][1] = p1;
            sp[w][lane][2] = p2;
            sp[w][lane][3] = p3;
            s0 += p0; s1 += p1; s2 += p2; s3 += p3;
        } else {  // zero-pad tail: contributes nothing, no divergence below
            soff[w][lane] = 0;
            sp[w][lane][0] = 0.f;
            sp[w][lane][1] = 0.f;
            sp[w][lane][2] = 0.f;
            sp[w][lane][3] = 0.f;
        }
        asm volatile("s_waitcnt lgkmcnt(0)" ::: "memory");
        int npair = (cnt + 1) >> 1;
        int t = 0;
        for (; t + 8 <= npair; t += 8) {  // 16 edges, 8 loads in flight
            int os[8];
            float ps[8];
            uint2 us[8];
#pragma unroll
            for (int i = 0; i < 8; ++i) {
                int e = 2 * (t + i) + half;
                os[i] = soff[w][e];
                ps[i] = sp[w][e][hd];
            }
#pragma unroll
            for (int i = 0; i < 8; ++i) us[i] = *(const uint2*)(hb + os[i] + fb);
#pragma unroll
            for (int i = 0; i < 8; ++i) {
                acc0 += ps[i] * blo(us[i].x);
                acc1 += ps[i] * bhi(us[i].x);
                acc2 += ps[i] * blo(us[i].y);
                acc3 += ps[i] * bhi(us[i].y);
            }
        }
        for (; t < npair; ++t) {
            int e = 2 * t + half;
            int o = soff[w][e];
            float p = sp[w][e][hd];
            uint2 u = *(const uint2*)(hb + o + fb);
            acc0 += p * blo(u.x);
            acc1 += p * bhi(u.x);
            acc2 += p * blo(u.y);
            acc3 += p * bhi(u.y);
        }
    }
    // combine the two half-waves
    acc0 += __shfl_xor(acc0, 32);
    acc1 += __shfl_xor(acc1, 32);
    acc2 += __shfl_xor(acc2, 32);
    acc3 += __shfl_xor(acc3, 32);
#pragma unroll
    for (int o = 32; o > 0; o >>= 1) {
        s0 += __shfl_xor(s0, o);
        s1 += __shfl_xor(s1, o);
        s2 += __shfl_xor(s2, o);
        s3 += __shfl_xor(s3, o);
    }
    s0 += ps0; s1 += ps1; s2 += ps2; s3 += ps3;
    float ssel = hd == 0 ? s0 : hd == 1 ? s1 : hd == 2 ? s2 : s3;
    float inv = 1.f / (ssel + 1e-16f);
    float4 bv = *(const float4*)&bias[sl << 2];
    float o0 = lrelu(acc0 * inv + bv.x, 0.01f);
    float o1 = lrelu(acc1 * inv + bv.y, 0.01f);
    float o2 = lrelu(acc2 * inv + bv.z, 0.01f);
    float o3 = lrelu(acc3 * inv + bv.w, 0.01f);
    if (do_l1) {
        float tsum = fabsf(o0) + fabsf(o1) + fabsf(o2) + fabsf(o3);
#pragma unroll
        for (int o = 16; o > 0; o >>= 1) tsum += __shfl_xor(tsum, o);  // 32-lane group
        float li = 1.f / fmaxf(tsum, 1e-12f);
        o0 *= li;
        o1 *= li;
        o2 *= li;
        o3 *= li;
    }
    if (half == 0) {
        uint2 pk;
        pk.x = ((unsigned)f2b(o0)) | (((unsigned)f2b(o1)) << 16);
        pk.y = ((unsigned)f2b(o2)) | (((unsigned)f2b(o3)) << 16);
        *(uint2*)((char*)out + (size_t)v * 256 + fb) = pk;
    }
}

// ---------------- GAT aggregation, 1 head (F=64), wave per dst node -----------------
// 16-lane group per edge (4 edges/iter), 4-deep unroll -> 16 edges/iter, 4 chains in flight.
// Self-loop seeded in group 0 ONLY.

__global__ __launch_bounds__(256) void agg1_kernel(
    const char* __restrict__ hb, const float* __restrict__ als, const float* __restrict__ ald,
    const int* __restrict__ offs, const int* __restrict__ cur, const int* __restrict__ csr,
    const float* __restrict__ bias, float* __restrict__ out, int n) {
    __shared__ int soff[4][64];
    __shared__ float sp[4][64];
    int w = threadIdx.x >> 6;
    int v = blockIdx.x * 4 + w;
    if (v >= n) return;
    int lane = threadIdx.x & 63;
    int grp = lane >> 4;
    int sl = lane & 15;
    int fb = sl << 3;  // byte offset of lane's 4 features
    float aldv = ald[v];
    float alsv = als[v];
    int begin = offs[v], end = cur[v];

    float pself = __expf(lrelu(alsv + aldv, 0.2f));
    float pseed = (grp == 0) ? pself : 0.f;
    uint2 uv = *(const uint2*)(hb + (size_t)v * 128 + fb);
    float acc0 = pseed * blo(uv.x);
    float acc1 = pseed * bhi(uv.x);
    float acc2 = pseed * blo(uv.y);
    float acc3 = pseed * bhi(uv.y);
    float ssum = 0.f;

    for (int base = begin; base < end; base += 64) {
        int idx = base + lane;
        int cnt = min(64, end - base);
        if (idx < end) {
            int s = csr[idx];
            float p = __expf(lrelu(als[s] + aldv, 0.2f));
            soff[w][lane] = s << 7;
            sp[w][lane] = p;
            ssum += p;
        } else {
            soff[w][lane] = 0;
            sp[w][lane] = 0.f;
        }
        asm volatile("s_waitcnt lgkmcnt(0)" ::: "memory");
        int nq = (cnt + 3) >> 2;
        int t = 0;
        for (; t + 4 <= nq; t += 4) {  // 16 edges, 4 loads in flight
            int os[4];
            float ps[4];
            uint2 us[4];
#pragma unroll
            for (int i = 0; i < 4; ++i) {
                int e = 4 * (t + i) + grp;
                os[i] = soff[w][e];
                ps[i] = sp[w][e];
            }
#pragma unroll
            for (int i = 0; i < 4; ++i) us[i] = *(const uint2*)(hb + os[i] + fb);
#pragma unroll
            for (int i = 0; i < 4; ++i) {
                acc0 += ps[i] * blo(us[i].x);
                acc1 += ps[i] * bhi(us[i].x);
                acc2 += ps[i] * blo(us[i].y);
                acc3 += ps[i] * bhi(us[i].y);
            }
        }
        for (; t < nq; ++t) {
            int e = 4 * t + grp;
            int o = soff[w][e];
            float p = sp[w][e];
            uint2 u = *(const uint2*)(hb + o + fb);
            acc0 += p * blo(u.x);
            acc1 += p * bhi(u.x);
            acc2 += p * blo(u.y);
            acc3 += p * bhi(u.y);
        }
    }
    // combine the four 16-lane groups
    acc0 += __shfl_xor(acc0, 32);
    acc1 += __shfl_xor(acc1, 32);
    acc2 += __shfl_xor(acc2, 32);
    acc3 += __shfl_xor(acc3, 32);
    acc0 += __shfl_xor(acc0, 16);
    acc1 += __shfl_xor(acc1, 16);
    acc2 += __shfl_xor(acc2, 16);
    acc3 += __shfl_xor(acc3, 16);
#pragma unroll
    for (int o = 32; o > 0; o >>= 1) ssum += __shfl_xor(ssum, o);
    ssum += pself;
    float inv = 1.f / (ssum + 1e-16f);
    float4 bv = *(const float4*)&bias[sl << 2];
    float o0 = acc0 * inv + bv.x;
    float o1 = acc1 * inv + bv.y;
    float o2 = acc2 * inv + bv.z;
    float o3 = acc3 * inv + bv.w;
    float tsum = fabsf(o0) + fabsf(o1) + fabsf(o2) + fabsf(o3);
#pragma unroll
    for (int o = 8; o > 0; o >>= 1) tsum += __shfl_xor(tsum, o);  // 16-lane group
    float li = 1.f / fmaxf(tsum, 1e-12f);
    if (grp == 0) {
        *(float4*)&out[(size_t)v * 64 + (sl << 2)] =
            make_float4(fmaxf(o0 * li, 0.f), fmaxf(o1 * li, 0.f), fmaxf(o2 * li, 0.f),
                        fmaxf(o3 * li, 0.f));
    }
}

// ---------------- launch ----------------

extern "C" void kernel_launch(void* const* d_in, const int* in_sizes, int n_in,
                              void* d_out, int out_size, void* d_ws, size_t ws_size,
                              hipStream_t stream) {
    const float* x = (const float*)d_in[0];
    const int* ei = (const int*)d_in[1];
    const float* W0 = (const float*)d_in[2];
    const float* b0 = (const float*)d_in[3];
    const float* as0 = (const float*)d_in[4];
    const float* ad0 = (const float*)d_in[5];
    const float* W1 = (const float*)d_in[6];
    const float* b1 = (const float*)d_in[7];
    const float* as1 = (const float*)d_in[8];
    const float* ad1 = (const float*)d_in[9];
    const float* W2 = (const float*)d_in[10];
    const float* b2 = (const float*)d_in[11];
    const float* as2 = (const float*)d_in[12];
    const float* ad2 = (const float*)d_in[13];
    float* outp = (float*)d_out;

    char* ws = (char*)d_ws;
    size_t off = 0;
    auto alloc = [&](size_t bytes) -> void* {
        void* p = ws + off;
        off = (off + bytes + 255) & ~(size_t)255;
        return p;
    };
    int* offs = (int*)alloc((NN + 1) * 4);
    int* bcnt = (int*)alloc(NB * 4);
    int* bbase = (int*)alloc((NB + 1) * 4);
    int* bcursor = (int*)alloc(NB * 4);
    int2* part = (int2*)alloc((size_t)NE * 8);
    int* csr = (int*)alloc((size_t)NE * 4);
    unsigned short* h16 = (unsigned short*)alloc((size_t)NN * 128 * 2);
    unsigned short* a16 = (unsigned short*)alloc((size_t)NN * 128 * 2);
    float* als = (float*)alloc(NN * 4 * 4);
    float* ald = (float*)alloc(NN * 4 * 4);

    const int* srcs = ei;
    const int* dsts = ei + NE;

    // CSR build
    hipMemsetAsync(bcnt, 0, NB * 4, stream);
    bucket_hist<<<NB, 256, 0, stream>>>(dsts, bcnt);
    bucket_scan<<<1, 512, 0, stream>>>(bcnt, bbase, bcursor);
    partition_kernel<<<(NE + CHUNK - 1) / CHUNK, 256, 0, stream>>>(srcs, dsts, bcursor, part);
    bucket_fill<<<NB, 256, 0, stream>>>(part, bbase, offs, csr);

    int ggrid = (NN + 63) / 64;
    int aggrid = (NN + 3) / 4;

    // layer 0
    gemm_fused<128, 4, true><<<ggrid, 256, 0, stream>>>(x, nullptr, W0, as0, ad0, h16, als, ald,
                                                        NN);
    agg4_kernel<<<aggrid, 256, 0, stream>>>((const char*)h16, als, ald, offs, offs + 1, csr, b0,
                                            (__hip_bfloat16*)a16, NN, 1);
    // layer 1
    gemm_fused<128, 4, false><<<ggrid, 256, 0, stream>>>(nullptr, a16, W1, as1, ad1, h16, als,
                                                         ald, NN);
    agg4_kernel<<<aggrid, 256, 0, stream>>>((const char*)h16, als, ald, offs, offs + 1, csr, b1,
                                            (__hip_bfloat16*)a16, NN, 0);
    // layer 2
    gemm_fused<64, 1, false><<<ggrid, 256, 0, stream>>>(nullptr, a16, W2, as2, ad2, h16, als,
                                                        ald, NN);
    agg1_kernel<<<aggrid, 256, 0, stream>>>((const char*)h16, als, ald, offs, offs + 1, csr, b2,
                                            outp, NN);
}

// Round 9
// 380.310 us; speedup vs baseline: 1.1250x; 1.1250x over previous
//
#include <hip/hip_runtime.h>
#include <hip/hip_bf16.h>

#define NN 100000
#define NE 1600000
#define NB 391      // buckets of 256 nodes: (100000 + 255) >> 8
#define CHUNK 4096  // edges per partition block

typedef short bf8v __attribute__((ext_vector_type(8)));   // 8 bf16 (4 VGPRs)
typedef float f32x4 __attribute__((ext_vector_type(4)));  // MFMA acc

static __device__ __forceinline__ float lrelu(float x, float s) {
    return x > 0.f ? x : s * x;
}

static __device__ __forceinline__ unsigned short f2b(float f) {
    __hip_bfloat16 b = __float2bfloat16(f);
    return *reinterpret_cast<unsigned short*>(&b);
}

static __device__ __forceinline__ float blo(unsigned u) {
    return __uint_as_float(u << 16);
}
static __device__ __forceinline__ float bhi(unsigned u) {
    return __uint_as_float(u & 0xFFFF0000u);
}

struct alignas(4) bh2 {
    __hip_bfloat16 x, y;
};

// ---------------- CSR build: two-level counting sort ----------------
// part entries packed as (dst&255)<<24 | src  (src < 2^17 -> fits 24 bits)

__global__ __launch_bounds__(256) void bucket_hist(const int* __restrict__ dsts,
                                                   int* __restrict__ bcnt) {
    __shared__ int hist[NB];
    for (int t = threadIdx.x; t < NB; t += 256) hist[t] = 0;
    __syncthreads();
    int stride = gridDim.x * 256;
    for (int e = blockIdx.x * 256 + threadIdx.x; e < NE; e += stride)
        atomicAdd(&hist[dsts[e] >> 8], 1);
    __syncthreads();
    for (int t = threadIdx.x; t < NB; t += 256) {
        int c = hist[t];
        if (c) atomicAdd(&bcnt[t], c);
    }
}

__global__ __launch_bounds__(512) void bucket_scan(const int* __restrict__ bcnt,
                                                   int* __restrict__ bbase,
                                                   int* __restrict__ bcursor) {
    __shared__ int sd[512];
    int t = threadIdx.x;
    int v = (t < NB) ? bcnt[t] : 0;
    sd[t] = v;
    __syncthreads();
    for (int off = 1; off < 512; off <<= 1) {
        int x = (t >= off) ? sd[t - off] : 0;
        __syncthreads();
        sd[t] += x;
        __syncthreads();
    }
    int excl = sd[t] - v;
    if (t < NB) {
        bbase[t] = excl;
        bcursor[t] = excl;
    }
    if (t == NB - 1) bbase[NB] = excl + v;
}

__global__ __launch_bounds__(256) void partition_kernel(const int* __restrict__ srcs,
                                                        const int* __restrict__ dsts,
                                                        int* bcursor,
                                                        unsigned* __restrict__ part) {
    __shared__ int hist[NB];
    __shared__ int lbase[NB];
    for (int t = threadIdx.x; t < NB; t += 256) hist[t] = 0;
    __syncthreads();
    int e0 = blockIdx.x * CHUNK;
#pragma unroll
    for (int k = 0; k < CHUNK / 256; k++) {
        int e = e0 + k * 256 + threadIdx.x;
        if (e < NE) atomicAdd(&hist[dsts[e] >> 8], 1);
    }
    __syncthreads();
    for (int t = threadIdx.x; t < NB; t += 256) {
        int c = hist[t];
        if (c) lbase[t] = atomicAdd(&bcursor[t], c);
        hist[t] = 0;  // reuse as local cursor
    }
    __syncthreads();
#pragma unroll
    for (int k = 0; k < CHUNK / 256; k++) {
        int e = e0 + k * 256 + threadIdx.x;
        if (e < NE) {
            int s = srcs[e], d = dsts[e];
            int b = d >> 8;
            int r = atomicAdd(&hist[b], 1);
            part[lbase[b] + r] = (((unsigned)d & 255u) << 24) | (unsigned)s;
        }
    }
}

__global__ __launch_bounds__(256) void bucket_fill(const unsigned* __restrict__ part,
                                                   const int* __restrict__ bbase,
                                                   int* __restrict__ offs,
                                                   int* __restrict__ csr) {
    __shared__ int lcur[256];
    __shared__ int sd[256];
    int b = blockIdx.x;
    int t = threadIdx.x;
    int ebeg = bbase[b], eend = bbase[b + 1];
    int node0 = b << 8;
    int nNodes = min(256, NN - node0);
    lcur[t] = 0;
    __syncthreads();
    for (int e = ebeg + t; e < eend; e += 256) {
        unsigned p = part[e];
        atomicAdd(&lcur[p >> 24], 1);
    }
    __syncthreads();
    int cnt = lcur[t];
    sd[t] = cnt;
    __syncthreads();
    for (int off = 1; off < 256; off <<= 1) {
        int x = (t >= off) ? sd[t - off] : 0;
        __syncthreads();
        sd[t] += x;
        __syncthreads();
    }
    int start = ebeg + sd[t] - cnt;
    if (t < nNodes) offs[node0 + t] = start;
    if (b == NB - 1 && t == 0) offs[NN] = NE;
    lcur[t] = start;
    __syncthreads();
    for (int e = ebeg + t; e < eend; e += 256) {
        unsigned p = part[e];
        int pos = atomicAdd(&lcur[p >> 24], 1);
        csr[pos] = (int)(p & 0xFFFFFFu);
    }
}

// ---------------- fused MFMA GEMM + attention coefficients ----------------

template <int NOUT, int HEADS, bool AF32>
__global__ __launch_bounds__(256) void gemm_fused(
    const float* __restrict__ A32, const unsigned short* __restrict__ A16,
    const float* __restrict__ W, const float* __restrict__ asrc,
    const float* __restrict__ adst, unsigned short* __restrict__ h16out,
    float* __restrict__ als, float* __restrict__ ald, int n) {
    constexpr int NF = NOUT / 16;
    constexpr int PITCH = 136;
    __shared__ unsigned short Wl[NOUT * PITCH];

    const int tid = threadIdx.x;
    for (int i = tid; i < (128 * NOUT) / 4; i += 256) {
        int idx = i * 4;
        int k = idx / NOUT;
        int c = idx - k * NOUT;
        float4 wv = *(const float4*)&W[idx];
        Wl[(c + 0) * PITCH + k] = f2b(wv.x);
        Wl[(c + 1) * PITCH + k] = f2b(wv.y);
        Wl[(c + 2) * PITCH + k] = f2b(wv.z);
        Wl[(c + 3) * PITCH + k] = f2b(wv.w);
    }
    __syncthreads();

    const int lane = tid & 63, wave = tid >> 6;
    const int c = lane & 15, hi = lane >> 4;
    const int r0 = blockIdx.x * 64;
    const int arow = min(r0 + wave * 16 + c, n - 1);
    const int kb = hi * 8;

    f32x4 acc[NF];
#pragma unroll
    for (int nf = 0; nf < NF; ++nf) acc[nf] = 0;

#pragma unroll
    for (int kc = 0; kc < 4; ++kc) {
        bf8v a;
        if constexpr (AF32) {
            const float* ap = A32 + (size_t)arow * 128 + kc * 32 + kb;
            float4 f0 = *(const float4*)ap;
            float4 f1 = *(const float4*)(ap + 4);
            union {
                bf8v v;
                unsigned short u[8];
            } ua;
            ua.u[0] = f2b(f0.x);
            ua.u[1] = f2b(f0.y);
            ua.u[2] = f2b(f0.z);
            ua.u[3] = f2b(f0.w);
            ua.u[4] = f2b(f1.x);
            ua.u[5] = f2b(f1.y);
            ua.u[6] = f2b(f1.z);
            ua.u[7] = f2b(f1.w);
            a = ua.v;
        } else {
            a = *(const bf8v*)(A16 + (size_t)arow * 128 + kc * 32 + kb);
        }
#pragma unroll
        for (int nf = 0; nf < NF; ++nf) {
            bf8v b = *(const bf8v*)&Wl[(nf * 16 + c) * PITCH + kc * 32 + kb];
            acc[nf] = __builtin_amdgcn_mfma_f32_16x16x32_bf16(a, b, acc[nf], 0, 0, 0);
        }
    }

    // epilogue 1: als/ald from accumulators
    float aS[NF], aD[NF];
#pragma unroll
    for (int nf = 0; nf < NF; ++nf) {
        aS[nf] = asrc[nf * 16 + c];
        aD[nf] = adst[nf * 16 + c];
    }
    float sRes[HEADS][4], dRes[HEADS][4];
#pragma unroll
    for (int hh = 0; hh < HEADS; ++hh) {
#pragma unroll
        for (int reg = 0; reg < 4; ++reg) {
            float s = 0.f, d = 0.f;
#pragma unroll
            for (int nf = hh * (NF / HEADS); nf < (hh + 1) * (NF / HEADS); ++nf) {
                s += acc[nf][reg] * aS[nf];
                d += acc[nf][reg] * aD[nf];
            }
#pragma unroll
            for (int o = 1; o < 16; o <<= 1) {
                s += __shfl_xor(s, o);
                d += __shfl_xor(d, o);
            }
            sRes[hh][reg] = s;
            dRes[hh][reg] = d;
        }
    }
    if (c == 0) {
#pragma unroll
        for (int reg = 0; reg < 4; ++reg) {
            int ro = r0 + wave * 16 + hi * 4 + reg;
            if (ro < n) {
                if constexpr (HEADS == 4) {
                    *(float4*)&als[ro * 4] =
                        make_float4(sRes[0][reg], sRes[1][reg], sRes[2][reg], sRes[3][reg]);
                    *(float4*)&ald[ro * 4] =
                        make_float4(dRes[0][reg], dRes[1][reg], dRes[2][reg], dRes[3][reg]);
                } else {
                    als[ro] = sRes[0][reg];
                    ald[ro] = dRes[0][reg];
                }
            }
        }
    }

    // epilogue 2: h -> bf16 via LDS transpose, coalesced store
    __syncthreads();
#pragma unroll
    for (int nf = 0; nf < NF; ++nf) {
#pragma unroll
        for (int reg = 0; reg < 4; ++reg) {
            int rl = wave * 16 + hi * 4 + reg;
            Wl[rl * PITCH + nf * 16 + c] = f2b(acc[nf][reg]);
        }
    }
    __syncthreads();
    constexpr int SEGS = NOUT / 8;
    for (int i = tid; i < 64 * SEGS; i += 256) {
        int rl = i / SEGS, sg = i - rl * SEGS;
        int ro = r0 + rl;
        if (ro < n)
            *(uint4*)&h16out[(size_t)ro * NOUT + sg * 8] =
                *(const uint4*)&Wl[rl * PITCH + sg * 8];
    }
}

// ---------------- GAT aggregation, 4 heads (F=128), wave per dst node ----------------
// Round-5 structure: full-wave dword gather (one 256B row per instruction), 8 loads
// in flight. Lane owns feats (2*lane, 2*lane+1); head = lane>>4.

__global__ __launch_bounds__(256) void agg4_kernel(
    const char* __restrict__ hb, const float* __restrict__ als, const float* __restrict__ ald,
    const int* __restrict__ offs, const int* __restrict__ cur, const int* __restrict__ csr,
    const float* __restrict__ bias, __hip_bfloat16* __restrict__ out, int n, int do_l1) {
    __shared__ int soff[4][64];
    __shared__ float sp[4][64][4];
    int w = threadIdx.x >> 6;
    int v = blockIdx.x * 4 + w;
    if (v >= n) return;
    int lane = threadIdx.x & 63;
    int hd = lane >> 4;
    int lane4 = lane << 2;

    float4 av = *(const float4*)&ald[v * 4];
    float4 svv = *(const float4*)&als[v * 4];
    int begin = offs[v], end = cur[v];

    float ps0 = __expf(lrelu(svv.x + av.x, 0.2f));
    float ps1 = __expf(lrelu(svv.y + av.y, 0.2f));
    float ps2 = __expf(lrelu(svv.z + av.z, 0.2f));
    float ps3 = __expf(lrelu(svv.w + av.w, 0.2f));
    float psel = hd == 0 ? ps0 : hd == 1 ? ps1 : hd == 2 ? ps2 : ps3;
    unsigned uv = *(const unsigned*)(hb + (size_t)v * 256 + lane4);
    float acc0 = psel * blo(uv);
    float acc1 = psel * bhi(uv);
    float s0 = 0.f, s1 = 0.f, s2 = 0.f, s3 = 0.f;

    for (int base = begin; base < end; base += 64) {
        int idx = base + lane;
        int cnt = min(64, end - base);
        if (idx < end) {
            int s = csr[idx];
            float4 q = *(const float4*)&als[s * 4];
            float p0 = __expf(lrelu(q.x + av.x, 0.2f));
            float p1 = __expf(lrelu(q.y + av.y, 0.2f));
            float p2 = __expf(lrelu(q.z + av.z, 0.2f));
            float p3 = __expf(lrelu(q.w + av.w, 0.2f));
            soff[w][lane] = s << 8;  // byte offset into bf16 rows (128*2B)
            sp[w][lane][0] = p0;
            sp[w][lane][1] = p1;
            sp[w][lane][2] = p2;
            sp[w][lane][3] = p3;
            s0 += p0; s1 += p1; s2 += p2; s3 += p3;
        }
        asm volatile("s_waitcnt lgkmcnt(0)" ::: "memory");
        int t = 0;
        for (; t + 8 <= cnt; t += 8) {
            int o0 = soff[w][t + 0], o1 = soff[w][t + 1];
            int o2 = soff[w][t + 2], o3 = soff[w][t + 3];
            int o4 = soff[w][t + 4], o5 = soff[w][t + 5];
            int o6 = soff[w][t + 6], o7 = soff[w][t + 7];
            float p0 = sp[w][t + 0][hd], p1 = sp[w][t + 1][hd];
            float p2 = sp[w][t + 2][hd], p3 = sp[w][t + 3][hd];
            float p4 = sp[w][t + 4][hd], p5 = sp[w][t + 5][hd];
            float p6 = sp[w][t + 6][hd], p7 = sp[w][t + 7][hd];
            unsigned u0 = *(const unsigned*)(hb + o0 + lane4);
            unsigned u1 = *(const unsigned*)(hb + o1 + lane4);
            unsigned u2 = *(const unsigned*)(hb + o2 + lane4);
            unsigned u3 = *(const unsigned*)(hb + o3 + lane4);
            unsigned u4 = *(const unsigned*)(hb + o4 + lane4);
            unsigned u5 = *(const unsigned*)(hb + o5 + lane4);
            unsigned u6 = *(const unsigned*)(hb + o6 + lane4);
            unsigned u7 = *(const unsigned*)(hb + o7 + lane4);
            acc0 += p0 * blo(u0);
            acc1 += p0 * bhi(u0);
            acc0 += p1 * blo(u1);
            acc1 += p1 * bhi(u1);
            acc0 += p2 * blo(u2);
            acc1 += p2 * bhi(u2);
            acc0 += p3 * blo(u3);
            acc1 += p3 * bhi(u3);
            acc0 += p4 * blo(u4);
            acc1 += p4 * bhi(u4);
            acc0 += p5 * blo(u5);
            acc1 += p5 * bhi(u5);
            acc0 += p6 * blo(u6);
            acc1 += p6 * bhi(u6);
            acc0 += p7 * blo(u7);
            acc1 += p7 * bhi(u7);
        }
        for (; t < cnt; ++t) {
            int oa = soff[w][t];
            float pa = sp[w][t][hd];
            unsigned ua = *(const unsigned*)(hb + oa + lane4);
            acc0 += pa * blo(ua);
            acc1 += pa * bhi(ua);
        }
    }
#pragma unroll
    for (int o = 32; o > 0; o >>= 1) {
        s0 += __shfl_xor(s0, o);
        s1 += __shfl_xor(s1, o);
        s2 += __shfl_xor(s2, o);
        s3 += __shfl_xor(s3, o);
    }
    s0 += ps0; s1 += ps1; s2 += ps2; s3 += ps3;
    float ssel = hd == 0 ? s0 : hd == 1 ? s1 : hd == 2 ? s2 : s3;
    float inv = 1.f / (ssel + 1e-16f);
    float2 bv = *(const float2*)&bias[2 * lane];
    float o0 = lrelu(acc0 * inv + bv.x, 0.01f);
    float o1 = lrelu(acc1 * inv + bv.y, 0.01f);
    if (do_l1) {
        float t = fabsf(o0) + fabsf(o1);
#pragma unroll
        for (int o = 32; o > 0; o >>= 1) t += __shfl_xor(t, o);
        float li = 1.f / fmaxf(t, 1e-12f);
        o0 *= li;
        o1 *= li;
    }
    bh2 pk;
    pk.x = __float2bfloat16(o0);
    pk.y = __float2bfloat16(o1);
    *(bh2*)&out[(size_t)v * 128 + 2 * lane] = pk;
}

// ---------------- GAT aggregation, 1 head (F=64), wave per dst node (round-5) --------

__global__ __launch_bounds__(256) void agg1_kernel(
    const char* __restrict__ hb, const float* __restrict__ als, const float* __restrict__ ald,
    const int* __restrict__ offs, const int* __restrict__ cur, const int* __restrict__ csr,
    const float* __restrict__ bias, float* __restrict__ out, int n) {
    __shared__ int soff[4][64];
    __shared__ float sp[4][64];
    int w = threadIdx.x >> 6;
    int v = blockIdx.x * 4 + w;
    if (v >= n) return;
    int lane = threadIdx.x & 63;
    int lane2 = lane << 1;
    float aldv = ald[v];
    float alsv = als[v];
    int begin = offs[v], end = cur[v];

    float pself = __expf(lrelu(alsv + aldv, 0.2f));
    unsigned short usv = *(const unsigned short*)(hb + (size_t)v * 128 + lane2);
    float acc = pself * __uint_as_float(((unsigned)usv) << 16);
    float ssum = 0.f;

    for (int base = begin; base < end; base += 64) {
        int idx = base + lane;
        int cnt = min(64, end - base);
        if (idx < end) {
            int s = csr[idx];
            float p = __expf(lrelu(als[s] + aldv, 0.2f));
            soff[w][lane] = s << 7;  // byte offset into bf16 rows (64*2B)
            sp[w][lane] = p;
            ssum += p;
        }
        asm volatile("s_waitcnt lgkmcnt(0)" ::: "memory");
        int t = 0;
        for (; t + 8 <= cnt; t += 8) {
            int o0 = soff[w][t + 0], o1 = soff[w][t + 1];
            int o2 = soff[w][t + 2], o3 = soff[w][t + 3];
            int o4 = soff[w][t + 4], o5 = soff[w][t + 5];
            int o6 = soff[w][t + 6], o7 = soff[w][t + 7];
            float p0 = sp[w][t + 0], p1 = sp[w][t + 1];
            float p2 = sp[w][t + 2], p3 = sp[w][t + 3];
            float p4 = sp[w][t + 4], p5 = sp[w][t + 5];
            float p6 = sp[w][t + 6], p7 = sp[w][t + 7];
            unsigned short u0 = *(const unsigned short*)(hb + o0 + lane2);
            unsigned short u1 = *(const unsigned short*)(hb + o1 + lane2);
            unsigned short u2 = *(const unsigned short*)(hb + o2 + lane2);
            unsigned short u3 = *(const unsigned short*)(hb + o3 + lane2);
            unsigned short u4 = *(const unsigned short*)(hb + o4 + lane2);
            unsigned short u5 = *(const unsigned short*)(hb + o5 + lane2);
            unsigned short u6 = *(const unsigned short*)(hb + o6 + lane2);
            unsigned short u7 = *(const unsigned short*)(hb + o7 + lane2);
            acc += p0 * __uint_as_float(((unsigned)u0) << 16);
            acc += p1 * __uint_as_float(((unsigned)u1) << 16);
            acc += p2 * __uint_as_float(((unsigned)u2) << 16);
            acc += p3 * __uint_as_float(((unsigned)u3) << 16);
            acc += p4 * __uint_as_float(((unsigned)u4) << 16);
            acc += p5 * __uint_as_float(((unsigned)u5) << 16);
            acc += p6 * __uint_as_float(((unsigned)u6) << 16);
            acc += p7 * __uint_as_float(((unsigned)u7) << 16);
        }
        for (; t < cnt; ++t) {
            int oa = soff[w][t];
            float pa = sp[w][t];
            unsigned short ua = *(const unsigned short*)(hb + oa + lane2);
            acc += pa * __uint_as_float(((unsigned)ua) << 16);
        }
    }
#pragma unroll
    for (int o = 32; o > 0; o >>= 1) ssum += __shfl_xor(ssum, o);
    ssum += pself;
    float o = acc / (ssum + 1e-16f) + bias[lane];
    float t = fabsf(o);
#pragma unroll
    for (int off = 32; off > 0; off >>= 1) t += __shfl_xor(t, off);
    o = o / fmaxf(t, 1e-12f);
    out[(size_t)v * 64 + lane] = fmaxf(o, 0.f);
}

// ---------------- launch ----------------

extern "C" void kernel_launch(void* const* d_in, const int* in_sizes, int n_in,
                              void* d_out, int out_size, void* d_ws, size_t ws_size,
                              hipStream_t stream) {
    const float* x = (const float*)d_in[0];
    const int* ei = (const int*)d_in[1];
    const float* W0 = (const float*)d_in[2];
    const float* b0 = (const float*)d_in[3];
    const float* as0 = (const float*)d_in[4];
    const float* ad0 = (const float*)d_in[5];
    const float* W1 = (const float*)d_in[6];
    const float* b1 = (const float*)d_in[7];
    const float* as1 = (const float*)d_in[8];
    const float* ad1 = (const float*)d_in[9];
    const float* W2 = (const float*)d_in[10];
    const float* b2 = (const float*)d_in[11];
    const float* as2 = (const float*)d_in[12];
    const float* ad2 = (const float*)d_in[13];
    float* outp = (float*)d_out;

    char* ws = (char*)d_ws;
    size_t off = 0;
    auto alloc = [&](size_t bytes) -> void* {
        void* p = ws + off;
        off = (off + bytes + 255) & ~(size_t)255;
        return p;
    };
    int* offs = (int*)alloc((NN + 1) * 4);
    int* bcnt = (int*)alloc(NB * 4);
    int* bbase = (int*)alloc((NB + 1) * 4);
    int* bcursor = (int*)alloc(NB * 4);
    unsigned* part = (unsigned*)alloc((size_t)NE * 4);
    int* csr = (int*)alloc((size_t)NE * 4);
    unsigned short* h16 = (unsigned short*)alloc((size_t)NN * 128 * 2);
    unsigned short* a16 = (unsigned short*)alloc((size_t)NN * 128 * 2);
    float* als = (float*)alloc(NN * 4 * 4);
    float* ald = (float*)alloc(NN * 4 * 4);

    const int* srcs = ei;
    const int* dsts = ei + NE;

    // CSR build
    hipMemsetAsync(bcnt, 0, NB * 4, stream);
    bucket_hist<<<NB, 256, 0, stream>>>(dsts, bcnt);
    bucket_scan<<<1, 512, 0, stream>>>(bcnt, bbase, bcursor);
    partition_kernel<<<(NE + CHUNK - 1) / CHUNK, 256, 0, stream>>>(srcs, dsts, bcursor, part);
    bucket_fill<<<NB, 256, 0, stream>>>(part, bbase, offs, csr);

    int ggrid = (NN + 63) / 64;
    int aggrid = (NN + 3) / 4;

    // layer 0
    gemm_fused<128, 4, true><<<ggrid, 256, 0, stream>>>(x, nullptr, W0, as0, ad0, h16, als, ald,
                                                        NN);
    agg4_kernel<<<aggrid, 256, 0, stream>>>((const char*)h16, als, ald, offs, offs + 1, csr, b0,
                                            (__hip_bfloat16*)a16, NN, 1);
    // layer 1
    gemm_fused<128, 4, false><<<ggrid, 256, 0, stream>>>(nullptr, a16, W1, as1, ad1, h16, als,
                                                         ald, NN);
    agg4_kernel<<<aggrid, 256, 0, stream>>>((const char*)h16, als, ald, offs, offs + 1, csr, b1,
                                            (__hip_bfloat16*)a16, NN, 0);
    // layer 2
    gemm_fused<64, 1, false><<<ggrid, 256, 0, stream>>>(nullptr, a16, W2, as2, ad2, h16, als,
                                                        ald, NN);
    agg1_kernel<<<aggrid, 256, 0, stream>>>((const char*)h16, als, ald, offs, offs + 1, csr, b2,
                                            outp, NN);
}